// Round 7
// baseline (341.956 us; speedup 1.0000x reference)
//
#include <hip/hip_runtime.h>
#include <hip/hip_fp16.h>

#define LN_EPS 1e-5f

typedef _Float16 f16x2 __attribute__((ext_vector_type(2)));
typedef _Float16 f16x8 __attribute__((ext_vector_type(8)));

__device__ __forceinline__ void pk_atomic_add_u32(_Float16* p, unsigned bits) {
  f16x2 v = __builtin_bit_cast(f16x2, bits);
#if __has_builtin(__builtin_amdgcn_flat_atomic_fadd_v2f16)
  __builtin_amdgcn_flat_atomic_fadd_v2f16((f16x2*)p, v);
#else
  unsafeAtomicAdd((__half2*)p, *(__half2*)&v);
#endif
}

__device__ __forceinline__ unsigned pack2(float a, float b) {
  f16x2 v;
  v.x = (_Float16)a;
  v.y = (_Float16)b;
  return __builtin_bit_cast(unsigned, v);
}

// ---------------------------------------------------------------------------
// Algebra: per-edge contribution to the (pre-mean) node feature is
//   contrib[col] = sum_h a_h (rel . M_h[col] + cv_h[col])
// linear in f = (a0,a1,a2, rx,ry,rz, a_h*rel_i for h<3, 1)  [16 dims]
// (sum_h a_h = 1 eliminates head 3). scatter-mean(contrib) = scatter-mean(f) @ T.
// f[15] = 1 doubles as the count. f accumulated in f16 via packed atomics.
//
// Round-7: three atomic theories falsified (count R4, line-contention R6,
// DS-transpose R3 ~5us) — the edge atomic core (~35us) is at a random-access
// floor. This round removes the ~20us AROUND it:
//  - memset dispatch folded into precompute (blocks 2+ zero fsums + barrier
//    counter; NREP=1 — R6's regression was the replication, not the fold);
//  - edge+node fused into ONE kernel with a software grid barrier (counter
//    pre-zeroed by the precompute DISPATCH -> no init race; dispatch
//    boundary flushes zeros to memory where the memory-side atomics RMW).
//    Co-residency for the spin barrier is guaranteed by
//    __launch_bounds__(256,4) (>=4 blocks/CU -> >=1024 co-resident) and
//    grid = ceil(nchunks/2) = 977 <= 1024, balanced 2 chunks/block.
//  - node phase hoists T into 16 registers per thread (loop-invariant
//    across its ~13 node iterations): T L2 traffic 200 MB -> 17 MB.
//
// ws layout: [0, N*32 B) f16 f-sums; then floats: coef[40] pad[8] T[512],
// u32 barrier counter at float index 560.
// ---------------------------------------------------------------------------

__global__ __launch_bounds__(256) void precompute_kernel(
    const float* __restrict__ Wq, const float* __restrict__ bq,
    const float* __restrict__ Wk, const float* __restrict__ bk,
    const float* __restrict__ Wv, const float* __restrict__ bv,
    const float* __restrict__ Wout, float* __restrict__ coef,
    float* __restrict__ T, unsigned* __restrict__ ctr,
    uint4* __restrict__ zbase, int zcount) {
  __shared__ float sW[1024];  // Wq[384] Wk[384] bq[128] bk[128]
  __shared__ float sM[4][3][32];
  __shared__ float sCv[4][32];
  const int t = threadIdx.x;
  const float scale = 0.17677669529663687f;  // 1/sqrt(32)

  if (blockIdx.x == 0) {
    // --- coef: stage Wq/Wk/bq/bk coalesced, then 40-thread LDS loop.
    for (int i = t; i < 384; i += 256) {
      sW[i] = Wq[i];
      sW[384 + i] = Wk[i];
    }
    if (t < 128) {
      sW[768 + t] = bq[t];
      sW[896 + t] = bk[t];
    }
    __syncthreads();

    if (t < 40) {
      const int h = t / 10, j = t % 10;
      float acc = 0.f;
#pragma unroll 4
      for (int d = 0; d < 32; ++d) {
        const int idx = h * 32 + d;
        float q0 = sW[idx], q1 = sW[128 + idx], q2 = sW[256 + idx];
        float k0 = sW[384 + idx], k1 = sW[512 + idx], k2 = sW[640 + idx];
        float bqv = sW[768 + idx], bkv = sW[896 + idx];
        float v;
        switch (j) {
          case 0: v = q0 * k0; break;
          case 1: v = q1 * k1; break;
          case 2: v = q2 * k2; break;
          case 3: v = q0 * k1 + q1 * k0; break;
          case 4: v = q0 * k2 + q2 * k0; break;
          case 5: v = q1 * k2 + q2 * k1; break;
          case 6: v = q0 * bkv + k0 * bqv; break;
          case 7: v = q1 * bkv + k1 * bqv; break;
          case 8: v = q2 * bkv + k2 * bqv; break;
          default: v = bqv * bkv; break;
        }
        acc += v;
      }
      coef[t] = acc * scale;
    }
  } else if (blockIdx.x == 1) {
    // --- T factors: 128 work items (h, o), each a 32-deep reduction.
    if (t < 128) {
      const int h = t >> 5, o = t & 31;
      float m0 = 0, m1 = 0, m2 = 0, cv = 0;
      for (int d = 0; d < 32; ++d) {
        const int j = h * 32 + d;
        const float w = Wout[j * 32 + o];  // coalesced across o
        m0 += Wv[j] * w;
        m1 += Wv[128 + j] * w;
        m2 += Wv[256 + j] * w;
        cv += bv[j] * w;
      }
      sM[h][0][o] = m0;
      sM[h][1][o] = m1;
      sM[h][2][o] = m2;
      sCv[h][o] = cv;
    }
    __syncthreads();

    if (t < 128) {
      for (int idx = t; idx < 512; idx += 128) {
        const int j = idx >> 5, col = idx & 31;
        float v;
        if (j < 3)        v = sCv[j][col] - sCv[3][col];
        else if (j < 6)   v = sM[3][j - 3][col];
        else if (j < 15)  { const int h2 = (j - 6) / 3, i = (j - 6) % 3; v = sM[h2][i][col] - sM[3][i][col]; }
        else              v = sCv[3][col];
        T[idx] = v;
      }
    }
  } else {
    // --- zero the f-sum accumulators + the soft-barrier counter
    // (replaces the hipMemsetAsync dispatch; flushed at dispatch boundary)
    if (blockIdx.x == 2 && t == 0) *ctr = 0u;
    const uint4 z = {0u, 0u, 0u, 0u};
    const int stride = (gridDim.x - 2) * 256;
    for (int i = (blockIdx.x - 2) * 256 + t; i < zcount; i += stride)
      zbase[i] = z;
  }
}

__global__ __launch_bounds__(256, 4) void fused_kernel(
    const float* __restrict__ pos, const int* __restrict__ ei, int E, int N,
    const float* __restrict__ coef, const float* __restrict__ T,
    const float* __restrict__ bout, const float* __restrict__ gamma,
    const float* __restrict__ beta, _Float16* __restrict__ fsums,
    unsigned* __restrict__ ctr, float* __restrict__ out, int nchunks) {
  __shared__ unsigned sF[8][264];  // slot-major packed f16x2, padded stride
  __shared__ int sC[256];

  const int t = threadIdx.x;
  const int lane64 = t & 63;

  // --- int64 layout probe, wave-local: odd 32-bit words of the first 8
  // indices are all zero iff buffer is little-endian int64.
  bool pz = true;
  if (lane64 < 8) pz = (ei[2 * lane64 + 1] == 0);
  const unsigned long long bz = __ballot(pz);
  const int i64 = (int)__builtin_amdgcn_readfirstlane(bz == ~0ull ? 1 : 0);

  // ===================== edge phase (grid-stride over chunks) ==============
  const int w = t >> 6;
  const int slot = lane64 & 7;
  const int esub = lane64 >> 3;

  for (int cb = blockIdx.x; cb < nchunks; cb += gridDim.x) {
    const int base = cb * 256;
    const int vb = min(256, E - base);
    const int e = base + t;

    if (t < vb) {
      int r, c;
      if (i64) {
        r = ((const int2*)ei)[(size_t)e].x;
        c = ((const int2*)ei)[(size_t)E + (size_t)e].x;
      } else {
        r = ei[e];
        c = ei[(size_t)E + e];
      }
      const float rx = pos[r * 3 + 0] - pos[c * 3 + 0];
      const float ry = pos[r * 3 + 1] - pos[c * 3 + 1];
      const float rz = pos[r * 3 + 2] - pos[c * 3 + 2];
      float s[4];
#pragma unroll
      for (int h = 0; h < 4; ++h) {
        const float* cf = coef + h * 10;  // uniform -> s_load
        s[h] = cf[9] + rx * cf[6] + ry * cf[7] + rz * cf[8] + rx * rx * cf[0] +
               ry * ry * cf[1] + rz * rz * cf[2] + rx * ry * cf[3] +
               rx * rz * cf[4] + ry * rz * cf[5];
      }
      const float mx = fmaxf(fmaxf(s[0], s[1]), fmaxf(s[2], s[3]));
      const float e0 = __expf(s[0] - mx), e1 = __expf(s[1] - mx);
      const float e2 = __expf(s[2] - mx), e3 = __expf(s[3] - mx);
      const float inv = 1.0f / (e0 + e1 + e2 + e3);
      const float a0 = e0 * inv, a1 = e1 * inv, a2 = e2 * inv;  // a3 unused

      sC[t] = c;
      sF[0][t] = pack2(a0, a1);
      sF[1][t] = pack2(a2, rx);
      sF[2][t] = pack2(ry, rz);
      sF[3][t] = pack2(a0 * rx, a0 * ry);
      sF[4][t] = pack2(a0 * rz, a1 * rx);
      sF[5][t] = pack2(a1 * ry, a1 * rz);
      sF[6][t] = pack2(a2 * rx, a2 * ry);
      sF[7][t] = pack2(a2 * rz, 1.0f);
    }
    __syncthreads();

    // atomic phase: 8 lanes per edge, 8 edges per wave-instruction.
#pragma unroll
    for (int i = 0; i < 8; ++i) {
      const int g = w * 64 + i * 8 + esub;
      if (g < vb) {
        const int ct = sC[g];
        const unsigned val = sF[slot][g];
        pk_atomic_add_u32(fsums + (size_t)ct * 16 + 2 * slot, val);
      }
    }
    __syncthreads();  // protect LDS reuse across chunk iterations
  }

  // ===================== software grid barrier =============================
  __threadfence();  // drain my atomics (vmcnt) + agent-release
  if (t == 0) {
    atomicAdd(ctr, 1u);
    while (atomicAdd(ctr, 0u) < (unsigned)gridDim.x)  // memory-side read
      __builtin_amdgcn_s_sleep(8);
  }
  __syncthreads();
  __threadfence();  // agent-acquire: invalidate stale cached fsums lines

  // ===================== node phase (grid-stride over nodes) ===============
  const int col = t & 31;
  float tc[16];
#pragma unroll
  for (int j = 0; j < 16; ++j) tc[j] = T[j * 32 + col];  // loop-invariant
  const float bo = bout[col], ga = gamma[col], be = beta[col];

  const int groups = gridDim.x * 8;  // 8 node-groups of 32 lanes per block
  for (int node = blockIdx.x * 8 + (t >> 5); node < N; node += groups) {
    const f16x8* fp = (const f16x8*)(fsums + (size_t)node * 16);
    const f16x8 va = fp[0];
    const f16x8 vb = fp[1];
    float f[16];
#pragma unroll
    for (int j = 0; j < 8; ++j) {
      f[j] = (float)va[j];
      f[8 + j] = (float)vb[j];
    }
    const float invc = 1.0f / fmaxf(f[15], 1.0f);

    float acc = 0.f;
#pragma unroll
    for (int j = 0; j < 16; ++j) acc = fmaf(f[j], tc[j], acc);
    acc = fmaf(acc, invc, bo);

    float sx = acc, sx2 = acc * acc;
#pragma unroll
    for (int off = 16; off >= 1; off >>= 1) {
      sx += __shfl_xor(sx, off);
      sx2 += __shfl_xor(sx2, off);
    }
    const float mu = sx * (1.0f / 32.0f);
    const float var = sx2 * (1.0f / 32.0f) - mu * mu;
    const float inv = rsqrtf(var + LN_EPS);
    const float y = (acc - mu) * inv * ga + be;
    const float o = y * (1.0f / (1.0f + __expf(-y)));  // SiLU
    out[(size_t)node * 32 + col] = o;
  }
}

extern "C" void kernel_launch(void* const* d_in, const int* in_sizes, int n_in,
                              void* d_out, int out_size, void* d_ws, size_t ws_size,
                              hipStream_t stream) {
  const float* pos  = (const float*)d_in[0];
  const int*   ei   = (const int*)d_in[1];
  const float* Wq   = (const float*)d_in[2];
  const float* bq   = (const float*)d_in[3];
  const float* Wk   = (const float*)d_in[4];
  const float* bk   = (const float*)d_in[5];
  const float* Wv   = (const float*)d_in[6];
  const float* bv   = (const float*)d_in[7];
  const float* Wout = (const float*)d_in[8];
  const float* bout = (const float*)d_in[9];
  const float* gam  = (const float*)d_in[10];
  const float* bet  = (const float*)d_in[11];

  const int N = in_sizes[0] / 3;
  const int E = in_sizes[1] / 2;

  _Float16* fsums = (_Float16*)d_ws;                     // N*16 halves
  float* coef = (float*)((char*)d_ws + (size_t)N * 32);  // 40 (+8 pad)
  float* T = coef + 48;                                  // 512
  unsigned* ctr = (unsigned*)(coef + 560);               // 1 u32

  const int zcount = (int)(((size_t)N * 32) / 16);       // uint4 units
  precompute_kernel<<<130, 256, 0, stream>>>(Wq, bq, Wk, bk, Wv, bv, Wout,
                                             coef, T, ctr, (uint4*)d_ws,
                                             zcount);

  const int nchunks = (E + 255) / 256;
  int g = (nchunks + 1) / 2;  // 2 balanced chunks per block
  if (g > 1024) g = 1024;     // co-residency cap (__launch_bounds__(256,4))
  if (g < 1) g = 1;
  fused_kernel<<<g, 256, 0, stream>>>(pos, ei, E, N, coef, T, bout, gam, bet,
                                      fsums, ctr, (float*)d_out, nchunks);

  (void)n_in; (void)out_size; (void)ws_size;
}

// Round 8
// 133.567 us; speedup vs baseline: 2.5602x; 2.5602x over previous
//
#include <hip/hip_runtime.h>
#include <hip/hip_fp16.h>

#define LN_EPS 1e-5f

typedef _Float16 f16x2 __attribute__((ext_vector_type(2)));
typedef _Float16 f16x8 __attribute__((ext_vector_type(8)));

__device__ __forceinline__ void pk_atomic_add_u32(_Float16* p, unsigned bits) {
  f16x2 v = __builtin_bit_cast(f16x2, bits);
#if __has_builtin(__builtin_amdgcn_flat_atomic_fadd_v2f16)
  __builtin_amdgcn_flat_atomic_fadd_v2f16((f16x2*)p, v);
#else
  unsafeAtomicAdd((__half2*)p, *(__half2*)&v);
#endif
}

__device__ __forceinline__ unsigned pack2(float a, float b) {
  f16x2 v;
  v.x = (_Float16)a;
  v.y = (_Float16)b;
  return __builtin_bit_cast(unsigned, v);
}

// ---------------------------------------------------------------------------
// Algebra: per-edge contribution to the (pre-mean) node feature is
//   contrib[col] = sum_h a_h (rel . M_h[col] + cv_h[col])
// linear in f = (a0,a1,a2, rx,ry,rz, a_h*rel_i for h<3, 1)  [16 dims]
// (sum_h a_h = 1 eliminates head 3). scatter-mean(contrib) = scatter-mean(f) @ T.
// f[15] = 1 doubles as the count. f accumulated in f16 via packed atomics.
//
// Round-8 (recovery + consolidate). R7's fused kernel died on its own grid
// barrier (polling RMWs on one line serialized the arrivals: 261us, VALU 3%).
// Keep R5 (best, 136.7us) and apply only the two safe items R7 bundled:
//  - memset dispatch folded into precompute (blocks 2..129 zero fsums with
//    uint4 stores; R6 arithmetic shows fold ~-4us, NREP was the regression);
//  - node kernel grid-strides with T/bout/gamma/beta hoisted to registers
//    (loop-invariant over ~10 nodes/thread) and 1280 blocks.
// Edge kernel untouched (R5's lean version; atomic floor ~35us, three
// restructuring theories falsified in R3/R4/R6).
//
// ws layout: [0, N*32 B) f16 f-sums; then floats: coef[40] pad[8] T[512].
// ---------------------------------------------------------------------------

__global__ __launch_bounds__(256) void precompute_kernel(
    const float* __restrict__ Wq, const float* __restrict__ bq,
    const float* __restrict__ Wk, const float* __restrict__ bk,
    const float* __restrict__ Wv, const float* __restrict__ bv,
    const float* __restrict__ Wout, float* __restrict__ coef,
    float* __restrict__ T, uint4* __restrict__ zbase, int zcount) {
  __shared__ float sW[1024];  // Wq[384] Wk[384] bq[128] bk[128]
  __shared__ float sM[4][3][32];
  __shared__ float sCv[4][32];
  const int t = threadIdx.x;
  const float scale = 0.17677669529663687f;  // 1/sqrt(32)

  if (blockIdx.x == 0) {
    // --- coef: stage Wq/Wk/bq/bk coalesced, then 40-thread LDS loop.
    for (int i = t; i < 384; i += 256) {
      sW[i] = Wq[i];
      sW[384 + i] = Wk[i];
    }
    if (t < 128) {
      sW[768 + t] = bq[t];
      sW[896 + t] = bk[t];
    }
    __syncthreads();

    if (t < 40) {
      const int h = t / 10, j = t % 10;
      float acc = 0.f;
#pragma unroll 4
      for (int d = 0; d < 32; ++d) {
        const int idx = h * 32 + d;
        float q0 = sW[idx], q1 = sW[128 + idx], q2 = sW[256 + idx];
        float k0 = sW[384 + idx], k1 = sW[512 + idx], k2 = sW[640 + idx];
        float bqv = sW[768 + idx], bkv = sW[896 + idx];
        float v;
        switch (j) {
          case 0: v = q0 * k0; break;
          case 1: v = q1 * k1; break;
          case 2: v = q2 * k2; break;
          case 3: v = q0 * k1 + q1 * k0; break;
          case 4: v = q0 * k2 + q2 * k0; break;
          case 5: v = q1 * k2 + q2 * k1; break;
          case 6: v = q0 * bkv + k0 * bqv; break;
          case 7: v = q1 * bkv + k1 * bqv; break;
          case 8: v = q2 * bkv + k2 * bqv; break;
          default: v = bqv * bkv; break;
        }
        acc += v;
      }
      coef[t] = acc * scale;
    }
  } else if (blockIdx.x == 1) {
    // --- T factors: 128 work items (h, o), each a 32-deep reduction.
    if (t < 128) {
      const int h = t >> 5, o = t & 31;
      float m0 = 0, m1 = 0, m2 = 0, cv = 0;
      for (int d = 0; d < 32; ++d) {
        const int j = h * 32 + d;
        const float w = Wout[j * 32 + o];  // coalesced across o
        m0 += Wv[j] * w;
        m1 += Wv[128 + j] * w;
        m2 += Wv[256 + j] * w;
        cv += bv[j] * w;
      }
      sM[h][0][o] = m0;
      sM[h][1][o] = m1;
      sM[h][2][o] = m2;
      sCv[h][o] = cv;
    }
    __syncthreads();

    if (t < 128) {
      for (int idx = t; idx < 512; idx += 128) {
        const int j = idx >> 5, col = idx & 31;
        float v;
        if (j < 3)        v = sCv[j][col] - sCv[3][col];
        else if (j < 6)   v = sM[3][j - 3][col];
        else if (j < 15)  { const int h2 = (j - 6) / 3, i = (j - 6) % 3; v = sM[h2][i][col] - sM[3][i][col]; }
        else              v = sCv[3][col];
        T[idx] = v;
      }
    }
  } else {
    // --- zero the f-sum accumulators (replaces the hipMemsetAsync dispatch)
    const uint4 z = {0u, 0u, 0u, 0u};
    const int stride = (gridDim.x - 2) * 256;
    for (int i = (blockIdx.x - 2) * 256 + t; i < zcount; i += stride)
      zbase[i] = z;
  }
}

__global__ __launch_bounds__(256) void edge_kernel(
    const float* __restrict__ pos, const int* __restrict__ ei, int E,
    const float* __restrict__ coef, _Float16* __restrict__ fsums) {
  __shared__ unsigned sF[8][264];  // slot-major packed f16x2, padded stride
  __shared__ int sC[256];

  const int t = threadIdx.x;
  const int lane64 = t & 63;

  // --- int64 layout probe, wave-local (no barrier): odd 32-bit words of the
  // first 8 indices are all zero iff buffer is little-endian int64.
  bool pz = true;
  if (lane64 < 8) pz = (ei[2 * lane64 + 1] == 0);
  const unsigned long long bz = __ballot(pz);
  const int i64 = (int)__builtin_amdgcn_readfirstlane(bz == ~0ull ? 1 : 0);

  const int base = blockIdx.x * 256;
  const int vb = min(256, E - base);
  const int e = base + t;

  int c = 0;
  float px0 = 0, px1 = 0, px2 = 0, pc0 = 0, pc1 = 0, pc2 = 0;
  if (t < vb) {
    int r;
    if (i64) {
      r = ((const int2*)ei)[(size_t)e].x;
      c = ((const int2*)ei)[(size_t)E + (size_t)e].x;
    } else {
      r = ei[e];
      c = ei[(size_t)E + e];
    }
    px0 = pos[r * 3 + 0]; px1 = pos[r * 3 + 1]; px2 = pos[r * 3 + 2];
    pc0 = pos[c * 3 + 0]; pc1 = pos[c * 3 + 1]; pc2 = pos[c * 3 + 2];
  }

  // --- per-edge: softmax weights from uniform (scalar-loaded) coef
  if (t < vb) {
    const float rx = px0 - pc0;
    const float ry = px1 - pc1;
    const float rz = px2 - pc2;
    float s[4];
#pragma unroll
    for (int h = 0; h < 4; ++h) {
      const float* cf = coef + h * 10;  // uniform -> s_load
      s[h] = cf[9] + rx * cf[6] + ry * cf[7] + rz * cf[8] + rx * rx * cf[0] +
             ry * ry * cf[1] + rz * rz * cf[2] + rx * ry * cf[3] +
             rx * rz * cf[4] + ry * rz * cf[5];
    }
    const float mx = fmaxf(fmaxf(s[0], s[1]), fmaxf(s[2], s[3]));
    const float e0 = __expf(s[0] - mx), e1 = __expf(s[1] - mx);
    const float e2 = __expf(s[2] - mx), e3 = __expf(s[3] - mx);
    const float inv = 1.0f / (e0 + e1 + e2 + e3);
    const float a0 = e0 * inv, a1 = e1 * inv, a2 = e2 * inv;  // a3 not needed

    sC[t] = c;
    sF[0][t] = pack2(a0, a1);
    sF[1][t] = pack2(a2, rx);
    sF[2][t] = pack2(ry, rz);
    sF[3][t] = pack2(a0 * rx, a0 * ry);
    sF[4][t] = pack2(a0 * rz, a1 * rx);
    sF[5][t] = pack2(a1 * ry, a1 * rz);
    sF[6][t] = pack2(a2 * rx, a2 * ry);
    sF[7][t] = pack2(a2 * rz, 1.0f);
  }
  __syncthreads();

  // --- atomic phase: 8 lanes per edge, 8 edges per wave-instruction so one
  // wave-atomic touches few cachelines.
  const int w = t >> 6;
  const int slot = lane64 & 7;
  const int esub = lane64 >> 3;
#pragma unroll
  for (int i = 0; i < 8; ++i) {
    const int g = w * 64 + i * 8 + esub;
    if (g < vb) {
      const int ct = sC[g];
      const unsigned val = sF[slot][g];
      pk_atomic_add_u32(fsums + (size_t)ct * 16 + 2 * slot, val);
    }
  }
}

__global__ __launch_bounds__(256) void node_kernel(
    const _Float16* __restrict__ fsums, const float* __restrict__ T,
    const float* __restrict__ bout, const float* __restrict__ gamma,
    const float* __restrict__ beta, float* __restrict__ out, int N) {
  const int t = threadIdx.x;
  const int col = t & 31;

  // Loop-invariant hoists: T column, bias, LN params (per-thread registers).
  float tc[16];
#pragma unroll
  for (int j = 0; j < 16; ++j) tc[j] = T[j * 32 + col];
  const float bo = bout[col], ga = gamma[col], be = beta[col];

  const int groups = gridDim.x * 8;  // 8 node-groups of 32 lanes per block
  for (int node = blockIdx.x * 8 + (t >> 5); node < N; node += groups) {
    // All 32 lanes of a group read the same 32 B (two dwordx4 broadcasts).
    const f16x8* fp = (const f16x8*)(fsums + (size_t)node * 16);
    const f16x8 va = fp[0];
    const f16x8 vb = fp[1];
    float f[16];
#pragma unroll
    for (int j = 0; j < 8; ++j) {
      f[j] = (float)va[j];
      f[8 + j] = (float)vb[j];
    }
    const float invc = 1.0f / fmaxf(f[15], 1.0f);

    float acc = 0.f;
#pragma unroll
    for (int j = 0; j < 16; ++j) acc = fmaf(f[j], tc[j], acc);
    acc = fmaf(acc, invc, bo);

    float sx = acc, sx2 = acc * acc;
#pragma unroll
    for (int off = 16; off >= 1; off >>= 1) {
      sx += __shfl_xor(sx, off);
      sx2 += __shfl_xor(sx2, off);
    }
    const float mu = sx * (1.0f / 32.0f);
    const float var = sx2 * (1.0f / 32.0f) - mu * mu;
    const float inv = rsqrtf(var + LN_EPS);
    const float y = (acc - mu) * inv * ga + be;
    const float o = y * (1.0f / (1.0f + __expf(-y)));  // SiLU
    out[(size_t)node * 32 + col] = o;
  }
}

extern "C" void kernel_launch(void* const* d_in, const int* in_sizes, int n_in,
                              void* d_out, int out_size, void* d_ws, size_t ws_size,
                              hipStream_t stream) {
  const float* pos  = (const float*)d_in[0];
  const int*   ei   = (const int*)d_in[1];
  const float* Wq   = (const float*)d_in[2];
  const float* bq   = (const float*)d_in[3];
  const float* Wk   = (const float*)d_in[4];
  const float* bk   = (const float*)d_in[5];
  const float* Wv   = (const float*)d_in[6];
  const float* bv   = (const float*)d_in[7];
  const float* Wout = (const float*)d_in[8];
  const float* bout = (const float*)d_in[9];
  const float* gam  = (const float*)d_in[10];
  const float* bet  = (const float*)d_in[11];

  const int N = in_sizes[0] / 3;
  const int E = in_sizes[1] / 2;

  _Float16* fsums = (_Float16*)d_ws;                     // N*16 halves
  float* coef = (float*)((char*)d_ws + (size_t)N * 32);  // 40 (+8 pad)
  float* T = coef + 48;                                  // 512

  const int zcount = (int)(((size_t)N * 32) / 16);       // uint4 units
  precompute_kernel<<<130, 256, 0, stream>>>(Wq, bq, Wk, bk, Wv, bv, Wout,
                                             coef, T, (uint4*)d_ws, zcount);

  const int edge_blocks = (E + 255) / 256;  // one edge per thread
  edge_kernel<<<edge_blocks, 256, 0, stream>>>(pos, ei, E, coef, fsums);

  int node_blocks = (N + 8 * 10 - 1) / (8 * 10);  // ~10 nodes per group
  if (node_blocks > 2048) node_blocks = 2048;
  node_kernel<<<node_blocks, 256, 0, stream>>>(fsums, T, bout, gam, bet,
                                               (float*)d_out, N);

  (void)n_in; (void)out_size; (void)ws_size;
}